// Round 2
// baseline (1122.547 us; speedup 1.0000x reference)
//
#include <hip/hip_runtime.h>
#include <hip/hip_bf16.h>

// Problem constants
#define BB 16
#define CIN 512
#define LL 2048
#define HEADS 4
#define KK 16
#define VVC 128
#define EPSV 1e-5f

__device__ __forceinline__ float bf2f(unsigned short u) {
    union { unsigned int i; float f; } c;
    c.i = ((unsigned int)u) << 16;
    return c.f;
}
__device__ __forceinline__ unsigned short f2bf(float f) {
    __hip_bfloat16 h = __float2bfloat16(f);
    union { __hip_bfloat16 h; unsigned short u; } c; c.h = h;
    return c.u;
}
// dtype-flexible external load: isbf==1 -> bf16, else fp32
__device__ __forceinline__ float loadIn(const void* p, size_t i, int isbf) {
    if (isbf) return bf2f(((const unsigned short*)p)[i]);
    return ((const float*)p)[i];
}
__device__ __forceinline__ void storeOut(void* p, size_t i, float v, int isbf) {
    if (isbf) ((unsigned short*)p)[i] = f2bf(v);
    else      ((float*)p)[i] = v;
}

// -------- Kernel 0: dtype detector --------
// Sample even ushort indices of x. bf16 N(0,1): exponent field in [96,144]
// for essentially every element. fp32 read as ushorts: even indices are low
// mantissa halves -> uniform exponent field -> ~19% hit rate.
__global__ __launch_bounds__(256) void detect_kernel(const void* __restrict__ x,
                                                     int* __restrict__ flag)
{
    const unsigned short* u = (const unsigned short*)x;
    int tid = threadIdx.x;
    unsigned short v = u[tid * 2];
    int e = (v >> 7) & 0xFF;
    int ok = (e >= 96 && e <= 144) ? 1 : 0;
    __shared__ int cnt[256];
    cnt[tid] = ok; __syncthreads();
    for (int s = 128; s > 0; s >>= 1) {
        if (tid < s) cnt[tid] += cnt[tid + s];
        __syncthreads();
    }
    if (tid == 0) *flag = (cnt[0] >= 200) ? 1 : 0;
}

// ---------------- Kernel 1: fused conv (q|k|v) + BN ----------------
// x: [B][CIN][L]. Outputs fp32: qbuf [B][64][L] (BN), kbuf [B][16][L] (raw),
// vbuf [B][128][L] (BN).
#define TILE_N 128
#define CI_CHUNK 16
#define XS_STRIDE 132

__global__ __launch_bounds__(256) void conv_kernel(
    const void* __restrict__ x,
    const void* __restrict__ Wq,
    const void* __restrict__ Wk,
    const void* __restrict__ Wv,
    const void* __restrict__ qg, const void* __restrict__ qb,
    const void* __restrict__ qm, const void* __restrict__ qv,
    const void* __restrict__ vg, const void* __restrict__ vb,
    const void* __restrict__ vm, const void* __restrict__ vvar,
    const int* __restrict__ flag,
    float* __restrict__ qbuf, float* __restrict__ kbuf, float* __restrict__ vbuf)
{
    __shared__ __align__(16) float xs[CI_CHUNK][XS_STRIDE];
    __shared__ float wsm[CI_CHUNK][3][16];   // [ci][t][co] - lane-consecutive co

    const int isbf = *flag;
    const int tid = threadIdx.x;
    const int n0 = blockIdx.x * TILE_N;      // 16 tiles
    const int co_base = blockIdx.y * 16;     // 13 tiles -> 208 channels
    const int b = blockIdx.z;

    const void* wsrc;
    int co_off;
    if (co_base < 64)       { wsrc = Wq; co_off = co_base; }
    else if (co_base < 80)  { wsrc = Wk; co_off = co_base - 64; }
    else                    { wsrc = Wv; co_off = co_base - 80; }

    const int co = tid & 15;          // 16 channels
    const int nb = (tid >> 4) * 8;    // 16 groups x 8 positions = 128

    float acc[8];
#pragma unroll
    for (int j = 0; j < 8; j++) acc[j] = 0.f;

    for (int ci0 = 0; ci0 < CIN; ci0 += CI_CHUNK) {
        // stage x tile: rows ci0..ci0+15, cols n0-1 .. n0+128 (130 valid cols)
        for (int i = tid; i < CI_CHUNK * 130; i += 256) {
            int r = i / 130, c = i % 130;
            int gn = n0 + c - 1;
            float v = 0.f;
            if (gn >= 0 && gn < LL)
                v = loadIn(x, ((size_t)b * CIN + (ci0 + r)) * LL + gn, isbf);
            xs[r][c] = v;
        }
        // stage weights transposed [ci][t][co]
        for (int i = tid; i < 16 * CI_CHUNK * 3; i += 256) {
            int col = i / 48;
            int rem = i % 48;
            int ci = rem / 3, t = rem % 3;
            wsm[ci][t][col] = loadIn(wsrc,
                (size_t)(co_off + col) * (CIN * 3) + (ci0 + ci) * 3 + t, isbf);
        }
        __syncthreads();
#pragma unroll
        for (int ci = 0; ci < CI_CHUNK; ci++) {
            float w0 = wsm[ci][0][co];
            float w1 = wsm[ci][1][co];
            float w2 = wsm[ci][2][co];
            float4 xa = *(const float4*)&xs[ci][nb];
            float4 xb = *(const float4*)&xs[ci][nb + 4];
            float2 xc = *(const float2*)&xs[ci][nb + 8];
            float xv[10] = {xa.x, xa.y, xa.z, xa.w, xb.x, xb.y, xb.z, xb.w, xc.x, xc.y};
#pragma unroll
            for (int j = 0; j < 8; j++)
                acc[j] += w0 * xv[j] + w1 * xv[j + 1] + w2 * xv[j + 2];
        }
        __syncthreads();
    }

    // epilogue: BN (q, v) and store fp32
    const int gco = co_base + co;
    float scale = 1.f, shift = 0.f;
    float* dst;
    int dco, CL;
    if (gco < 64) {
        float g = loadIn(qg, gco, isbf), be = loadIn(qb, gco, isbf);
        float m = loadIn(qm, gco, isbf), va = loadIn(qv, gco, isbf);
        scale = g * rsqrtf(va + EPSV);
        shift = be - m * scale;
        dst = qbuf; dco = gco; CL = 64;
    } else if (gco < 80) {
        dst = kbuf; dco = gco - 64; CL = 16;
    } else {
        int c = gco - 80;
        float g = loadIn(vg, c, isbf), be = loadIn(vb, c, isbf);
        float m = loadIn(vm, c, isbf), va = loadIn(vvar, c, isbf);
        scale = g * rsqrtf(va + EPSV);
        shift = be - m * scale;
        dst = vbuf; dco = c; CL = 128;
    }
    float4 o0, o1;
    o0.x = acc[0] * scale + shift; o0.y = acc[1] * scale + shift;
    o0.z = acc[2] * scale + shift; o0.w = acc[3] * scale + shift;
    o1.x = acc[4] * scale + shift; o1.y = acc[5] * scale + shift;
    o1.z = acc[6] * scale + shift; o1.w = acc[7] * scale + shift;
    size_t base = ((size_t)b * CL + dco) * LL + n0 + nb;
    *(float4*)&dst[base] = o0;
    *(float4*)&dst[base + 4] = o1;
}

// ---------------- Kernel 2: softmax over n, in place on kbuf ----------------
__global__ __launch_bounds__(256) void softmax_kernel(float* __restrict__ kbuf)
{
    const int row = blockIdx.x;                  // B*16 = 256 rows
    float* p = kbuf + (size_t)row * LL;
    const int tid = threadIdx.x;
    __shared__ float red[256];

    float vals[8];
    float vmax = -1e30f;
#pragma unroll
    for (int j = 0; j < 8; j++) {
        vals[j] = p[tid + j * 256];
        vmax = fmaxf(vmax, vals[j]);
    }
    red[tid] = vmax;
    __syncthreads();
    for (int s = 128; s > 0; s >>= 1) {
        if (tid < s) red[tid] = fmaxf(red[tid], red[tid + s]);
        __syncthreads();
    }
    float m = red[0];
    __syncthreads();
    float sum = 0.f;
#pragma unroll
    for (int j = 0; j < 8; j++) {
        vals[j] = __expf(vals[j] - m);
        sum += vals[j];
    }
    red[tid] = sum;
    __syncthreads();
    for (int s = 128; s > 0; s >>= 1) {
        if (tid < s) red[tid] += red[tid + s];
        __syncthreads();
    }
    float inv = 1.f / red[0];
#pragma unroll
    for (int j = 0; j < 8; j++) p[tid + j * 256] = vals[j] * inv;
}

// ---------------- Kernel 3: lambda_c[b][k][v] = sum_n sm*v ----------------
__global__ __launch_bounds__(256) void lambdac_kernel(
    const float* __restrict__ sm, const float* __restrict__ vbuf,
    float* __restrict__ lc)
{
    const int wave = threadIdx.x >> 6;
    const int lane = threadIdx.x & 63;
    const int idx = blockIdx.x * 4 + wave;   // 0..32767
    const int b = idx >> 11;
    const int rem = idx & 2047;
    const int k = rem >> 7;
    const int v = rem & 127;
    const float* ps = sm + ((size_t)b * 16 + k) * LL;
    const float* pv = vbuf + ((size_t)b * 128 + v) * LL;
    float acc = 0.f;
    for (int n = lane; n < LL; n += 64) acc += ps[n] * pv[n];
#pragma unroll
    for (int off = 32; off > 0; off >>= 1) acc += __shfl_down(acc, off, 64);
    if (lane == 0) lc[idx] = acc;
}

// ---------------- Kernel 4: output ----------------
// out[b][h*128+v][n] = sum_k q[b][h*16+k][n]*lc[b][k][v] + (sum_k q*emb[k]) * v[b][v][n]
#define FT_N 256
__global__ __launch_bounds__(256) void final_kernel(
    const float* __restrict__ qbuf, const float* __restrict__ vbuf,
    const float* __restrict__ lc, const void* __restrict__ emb,
    const int* __restrict__ flag, void* __restrict__ out)
{
    __shared__ float qs[16][FT_N];
    __shared__ float lcs[16][128];
    __shared__ float es[16];
    const int isbf = *flag;
    const int tid = threadIdx.x;
    const int n0 = blockIdx.x * FT_N;   // 8 tiles
    const int h = blockIdx.y;           // 4
    const int b = blockIdx.z;           // 16

    for (int i = tid; i < 16 * FT_N; i += 256) {
        int r = i >> 8, c = i & 255;
        qs[r][c] = qbuf[((size_t)b * 64 + h * 16 + r) * LL + n0 + c];
    }
    for (int i = tid; i < 16 * 128; i += 256)
        lcs[i >> 7][i & 127] = lc[(size_t)b * 2048 + i];
    if (tid < 16) es[tid] = loadIn(emb, tid, isbf);
    __syncthreads();

    const int n = n0 + tid;
    float q[16];
    float s = 0.f;
#pragma unroll
    for (int k2 = 0; k2 < 16; k2++) {
        q[k2] = qs[k2][tid];
        s += q[k2] * es[k2];
    }
    const float* pv = vbuf + (size_t)b * 128 * LL + n;
    size_t obase = ((size_t)b * 512 + h * 128) * LL + n;
    for (int v = 0; v < 128; v++) {
        float lam = 0.f;
#pragma unroll
        for (int k2 = 0; k2 < 16; k2++) lam += q[k2] * lcs[k2][v];
        float vvv = pv[(size_t)v * LL];
        storeOut(out, obase + (size_t)v * LL, lam + s * vvv, isbf);
    }
}

extern "C" void kernel_launch(void* const* d_in, const int* in_sizes, int n_in,
                              void* d_out, int out_size, void* d_ws, size_t ws_size,
                              hipStream_t stream)
{
    const void* x   = d_in[0];
    const void* Wq  = d_in[1];
    const void* qg  = d_in[2];
    const void* qb  = d_in[3];
    const void* qm  = d_in[4];
    const void* qv  = d_in[5];
    const void* Wk  = d_in[6];
    const void* Wv  = d_in[7];
    const void* vg  = d_in[8];
    const void* vb  = d_in[9];
    const void* vm  = d_in[10];
    const void* vva = d_in[11];
    const void* emb = d_in[12];

    int* flag   = (int*)d_ws;                          // 16 floats reserved
    float* qbuf = (float*)d_ws + 16;                   // 16*64*2048
    float* kbuf = qbuf + (size_t)BB * 64 * LL;         // 16*16*2048
    float* vbuf = kbuf + (size_t)BB * 16 * LL;         // 16*128*2048
    float* lcb  = vbuf + (size_t)BB * 128 * LL;        // 16*16*128

    hipLaunchKernelGGL(detect_kernel, dim3(1), dim3(256), 0, stream, x, flag);

    dim3 cgrid(LL / TILE_N, 13, BB);
    hipLaunchKernelGGL(conv_kernel, cgrid, dim3(256), 0, stream,
                       x, Wq, Wk, Wv, qg, qb, qm, qv, vg, vb, vm, vva, flag,
                       qbuf, kbuf, vbuf);

    hipLaunchKernelGGL(softmax_kernel, dim3(BB * 16), dim3(256), 0, stream, kbuf);

    hipLaunchKernelGGL(lambdac_kernel, dim3(BB * 16 * 128 / 4), dim3(256), 0, stream,
                       kbuf, vbuf, lcb);

    hipLaunchKernelGGL(final_kernel, dim3(LL / FT_N, HEADS, BB), dim3(256), 0, stream,
                       qbuf, vbuf, lcb, emb, flag, d_out);
}

// Round 3
// 234.852 us; speedup vs baseline: 4.7798x; 4.7798x over previous
//
#include <hip/hip_runtime.h>
#include <hip/hip_bf16.h>

#define BB 16
#define CIN 512
#define LL 2048
#define HEADS 4
#define KK 16
#define VVC 128
#define EPSV 1e-5f

typedef __attribute__((ext_vector_type(8))) short bf16x8s;
typedef __attribute__((ext_vector_type(4))) float f32x4;

__device__ __forceinline__ unsigned short f2bf(float f) {
    union { float f; unsigned int i; } c; c.f = f;
    unsigned int x = c.i;
    unsigned int lsb = (x >> 16) & 1;
    x += 0x7fff + lsb;            // RNE
    return (unsigned short)(x >> 16);
}
__device__ __forceinline__ unsigned int pack2bf(float a, float b) {
    return (unsigned int)f2bf(a) | ((unsigned int)f2bf(b) << 16);
}

// ---------------- Kernel 0: weight repack fp32 -> bf16 LDS images ----------------
// Wpk layout: [cot 7][chunk 16][t 3][co 32][ci 40] bf16  (ci 32 real + 8 pad)
#define WCHUNK_U16 3840   // 3*32*40

__global__ __launch_bounds__(256) void prep_weights(
    const float* __restrict__ Wq, const float* __restrict__ Wk,
    const float* __restrict__ Wv, unsigned short* __restrict__ Wpk)
{
    int blk = blockIdx.x;             // 0..111 = cot*16 + chunk
    int cot = blk >> 4, chunk = blk & 15;
    int ci0 = chunk * 32;
    for (int i = threadIdx.x; i < WCHUNK_U16; i += 256) {
        int t = i / 1280, r = i % 1280, co = r / 40, ci = r % 40;
        float val = 0.f;
        int cop = cot * 32 + co;
        if (ci < 32) {
            int cig = ci0 + ci;
            if (cop < 64)        val = Wq[((size_t)cop * 512 + cig) * 3 + t];
            else if (cop < 80)   val = Wk[((size_t)(cop - 64) * 512 + cig) * 3 + t];
            else if (cop < 208)  val = Wv[((size_t)(cop - 80) * 512 + cig) * 3 + t];
        }
        Wpk[(size_t)blk * WCHUNK_U16 + i] = f2bf(val);
    }
}

// ---------------- Kernel 1: MFMA conv (q|k|v) + BN ----------------
// Implicit GEMM: out[co][n] = sum_t sum_ci W[co][ci][t] * x[ci][n+t-1]
// Block: 32 co x 256 n, 4 waves (each 32co x 64n), K chunks of 32 ci.
#define XSTRIDE 20      // u32 per n-row (16 ci-pairs + 4 pad)

__global__ __launch_bounds__(256) void conv_mfma(
    const float* __restrict__ x, const unsigned short* __restrict__ Wpk,
    const float* __restrict__ qg, const float* __restrict__ qb,
    const float* __restrict__ qm, const float* __restrict__ qv,
    const float* __restrict__ vg, const float* __restrict__ vb,
    const float* __restrict__ vm, const float* __restrict__ vvar,
    float* __restrict__ qbuf, float* __restrict__ kbuf, float* __restrict__ vbuf)
{
    __shared__ __align__(16) unsigned int xT[258 * XSTRIDE];     // 20640 B
    __shared__ __align__(16) unsigned short wA[WCHUNK_U16];      // 7680 B
    __shared__ float sscale[32], sshift[32];

    const int tid = threadIdx.x;
    const int wave = tid >> 6, lane = tid & 63;
    const int kq = lane >> 4, lm = lane & 15;
    const int n0 = blockIdx.x * 256;
    const int cot = blockIdx.y;
    const int b = blockIdx.z;

    // BN scale/shift for this block's 32 channels
    if (tid < 32) {
        int cop = cot * 32 + tid;
        float sc = 1.f, sh = 0.f;
        if (cop < 64) {
            float g = qg[cop], be = qb[cop], m = qm[cop], va = qv[cop];
            sc = g * rsqrtf(va + EPSV); sh = be - m * sc;
        } else if (cop >= 80 && cop < 208) {
            int c = cop - 80;
            float g = vg[c], be = vb[c], m = vm[c], va = vvar[c];
            sc = g * rsqrtf(va + EPSV); sh = be - m * sc;
        }
        sscale[tid] = sc; sshift[tid] = sh;
    }

    f32x4 acc[2][4];
#pragma unroll
    for (int i = 0; i < 2; i++)
#pragma unroll
        for (int j = 0; j < 4; j++) acc[i][j] = (f32x4){0.f, 0.f, 0.f, 0.f};

    const float* xb = x + (size_t)b * CIN * LL;

    for (int chunk = 0; chunk < 16; chunk++) {
        __syncthreads();
        // stage weights: straight uint4 copy of prepacked image
        {
            const uint4* src = (const uint4*)(Wpk + (size_t)(cot * 16 + chunk) * WCHUNK_U16);
            uint4* dst = (uint4*)wA;
            for (int i = tid; i < WCHUNK_U16 / 8; i += 256) dst[i] = src[i];
        }
        // stage x transposed: 16 ci-pairs x 256 cols (+2 halo)
        const int ci0 = chunk * 32;
        for (int i = tid; i < 4096; i += 256) {
            int p = i >> 8, nl = i & 255;
            float v0 = xb[(size_t)(ci0 + 2 * p) * LL + n0 + nl];
            float v1 = xb[(size_t)(ci0 + 2 * p + 1) * LL + n0 + nl];
            int row = nl + 1;
            int colp = p ^ (((row >> 2) & 3) << 2);
            xT[row * XSTRIDE + colp] = pack2bf(v0, v1);
        }
        if (tid < 32) {
            int p = tid >> 1, c = tid & 1;
            int gn = c ? (n0 + 256) : (n0 - 1);
            float v0 = 0.f, v1 = 0.f;
            if (gn >= 0 && gn < LL) {
                v0 = xb[(size_t)(ci0 + 2 * p) * LL + gn];
                v1 = xb[(size_t)(ci0 + 2 * p + 1) * LL + gn];
            }
            int row = c ? 257 : 0;
            int colp = p ^ (((row >> 2) & 3) << 2);
            xT[row * XSTRIDE + colp] = pack2bf(v0, v1);
        }
        __syncthreads();

#pragma unroll
        for (int t = 0; t < 3; t++) {
            bf16x8s aF0 = *(const bf16x8s*)&wA[t * 1280 + lm * 40 + kq * 8];
            bf16x8s aF1 = *(const bf16x8s*)&wA[t * 1280 + (16 + lm) * 40 + kq * 8];
#pragma unroll
            for (int fn = 0; fn < 4; fn++) {
                int row = wave * 64 + fn * 16 + lm + t;
                int cg = ((kq ^ ((row >> 2) & 3)) << 2);
                bf16x8s bF = *(const bf16x8s*)&xT[row * XSTRIDE + cg];
                acc[0][fn] = __builtin_amdgcn_mfma_f32_16x16x32_bf16(aF0, bF, acc[0][fn], 0, 0, 0);
                acc[1][fn] = __builtin_amdgcn_mfma_f32_16x16x32_bf16(aF1, bF, acc[1][fn], 0, 0, 0);
            }
        }
    }

    // epilogue: C layout col=lane&15 (n), row=(lane>>4)*4+reg (co)
#pragma unroll
    for (int cf = 0; cf < 2; cf++) {
#pragma unroll
        for (int fn = 0; fn < 4; fn++) {
#pragma unroll
            for (int r = 0; r < 4; r++) {
                int col = cf * 16 + kq * 4 + r;        // co_local
                int cop = cot * 32 + col;
                if (cop >= 208) continue;
                float val = acc[cf][fn][r] * sscale[col] + sshift[col];
                int nout = n0 + wave * 64 + fn * 16 + lm;
                if (cop < 64)
                    qbuf[((size_t)b * 64 + cop) * LL + nout] = val;
                else if (cop < 80)
                    kbuf[((size_t)b * 16 + (cop - 64)) * LL + nout] = val;
                else
                    vbuf[((size_t)b * 128 + (cop - 80)) * LL + nout] = val;
            }
        }
    }
}

// ---------------- Kernel 2: softmax over n, in place on kbuf ----------------
__global__ __launch_bounds__(256) void softmax_kernel(float* __restrict__ kbuf)
{
    const int row = blockIdx.x;                  // B*16 = 256 rows
    float* p = kbuf + (size_t)row * LL;
    const int tid = threadIdx.x;
    __shared__ float red[256];

    float vals[8];
    float vmax = -1e30f;
#pragma unroll
    for (int j = 0; j < 8; j++) {
        vals[j] = p[tid + j * 256];
        vmax = fmaxf(vmax, vals[j]);
    }
    red[tid] = vmax;
    __syncthreads();
    for (int s = 128; s > 0; s >>= 1) {
        if (tid < s) red[tid] = fmaxf(red[tid], red[tid + s]);
        __syncthreads();
    }
    float m = red[0];
    __syncthreads();
    float sum = 0.f;
#pragma unroll
    for (int j = 0; j < 8; j++) {
        vals[j] = __expf(vals[j] - m);
        sum += vals[j];
    }
    red[tid] = sum;
    __syncthreads();
    for (int s = 128; s > 0; s >>= 1) {
        if (tid < s) red[tid] += red[tid + s];
        __syncthreads();
    }
    float inv = 1.f / red[0];
#pragma unroll
    for (int j = 0; j < 8; j++) p[tid + j * 256] = vals[j] * inv;
}

// ---------------- Kernel 3: lambda_c[b][k][v] = sum_n sm*v ----------------
// wave task = (b, k, v-group-of-8); float4 loads; sm read shared across 8 v rows
__global__ __launch_bounds__(256) void lambdac_kernel(
    const float* __restrict__ sm, const float* __restrict__ vbuf,
    float* __restrict__ lc)
{
    const int wave = threadIdx.x >> 6;
    const int lane = threadIdx.x & 63;
    const int task = blockIdx.x * 4 + wave;   // 16*16*16 = 4096 tasks
    const int b = task >> 8;
    const int rem = task & 255;
    const int k = rem >> 4;
    const int vg = rem & 15;
    const float* ps = sm + ((size_t)b * 16 + k) * LL;
    const float* pv = vbuf + ((size_t)b * 128 + vg * 8) * LL;
    float acc[8];
#pragma unroll
    for (int i = 0; i < 8; i++) acc[i] = 0.f;
#pragma unroll
    for (int j = 0; j < 8; j++) {
        int n = (j * 64 + lane) * 4;
        float4 s4 = *(const float4*)&ps[n];
#pragma unroll
        for (int vi = 0; vi < 8; vi++) {
            float4 v4 = *(const float4*)&pv[(size_t)vi * LL + n];
            acc[vi] += s4.x * v4.x + s4.y * v4.y + s4.z * v4.z + s4.w * v4.w;
        }
    }
#pragma unroll
    for (int vi = 0; vi < 8; vi++) {
#pragma unroll
        for (int off = 32; off > 0; off >>= 1)
            acc[vi] += __shfl_xor(acc[vi], off, 64);
    }
    if (lane == 0) {
#pragma unroll
        for (int vi = 0; vi < 8; vi++)
            lc[((size_t)b * 16 + k) * 128 + vg * 8 + vi] = acc[vi];
    }
}

// ---------------- Kernel 4: output ----------------
// out[b][h*128+v][n] = sum_k q[b][h*16+k][n]*lc[b][k][v] + (sum_k q*emb[k]) * v[b][v][n]
#define FT_N 256
__global__ __launch_bounds__(256) void final_kernel(
    const float* __restrict__ qbuf, const float* __restrict__ vbuf,
    const float* __restrict__ lc, const float* __restrict__ emb,
    float* __restrict__ out)
{
    __shared__ float qs[16][FT_N];
    __shared__ float lcs[16][128];
    __shared__ float es[16];
    const int tid = threadIdx.x;
    const int n0 = blockIdx.x * FT_N;   // 8 tiles
    const int h = blockIdx.y;           // 4
    const int b = blockIdx.z;           // 16

    for (int i = tid; i < 16 * FT_N; i += 256) {
        int r = i >> 8, c = i & 255;
        qs[r][c] = qbuf[((size_t)b * 64 + h * 16 + r) * LL + n0 + c];
    }
    for (int i = tid; i < 16 * 128; i += 256)
        lcs[i >> 7][i & 127] = lc[(size_t)b * 2048 + i];
    if (tid < 16) es[tid] = emb[tid];
    __syncthreads();

    const int n = n0 + tid;
    float q[16];
    float s = 0.f;
#pragma unroll
    for (int k2 = 0; k2 < 16; k2++) {
        q[k2] = qs[k2][tid];
        s += q[k2] * es[k2];
    }
    const float* pv = vbuf + (size_t)b * 128 * LL + n;
    float* po = out + ((size_t)b * 512 + h * 128) * LL + n;
    for (int v = 0; v < 128; v++) {
        float lam = 0.f;
#pragma unroll
        for (int k2 = 0; k2 < 16; k2++) lam += q[k2] * lcs[k2][v];
        float vvv = pv[(size_t)v * LL];
        po[(size_t)v * LL] = lam + s * vvv;
    }
}

extern "C" void kernel_launch(void* const* d_in, const int* in_sizes, int n_in,
                              void* d_out, int out_size, void* d_ws, size_t ws_size,
                              hipStream_t stream)
{
    const float* x   = (const float*)d_in[0];
    const float* Wq  = (const float*)d_in[1];
    const float* qg  = (const float*)d_in[2];
    const float* qb  = (const float*)d_in[3];
    const float* qm  = (const float*)d_in[4];
    const float* qv  = (const float*)d_in[5];
    const float* Wk  = (const float*)d_in[6];
    const float* Wv  = (const float*)d_in[7];
    const float* vg  = (const float*)d_in[8];
    const float* vb  = (const float*)d_in[9];
    const float* vm  = (const float*)d_in[10];
    const float* vva = (const float*)d_in[11];
    const float* emb = (const float*)d_in[12];
    float* out = (float*)d_out;

    float* qbuf = (float*)d_ws;                        // 16*64*2048
    float* kbuf = qbuf + (size_t)BB * 64 * LL;         // 16*16*2048
    float* vbuf = kbuf + (size_t)BB * 16 * LL;         // 16*128*2048
    float* lcb  = vbuf + (size_t)BB * 128 * LL;        // 16*16*128
    unsigned short* Wpk = (unsigned short*)(lcb + (size_t)BB * 16 * 128);

    hipLaunchKernelGGL(prep_weights, dim3(112), dim3(256), 0, stream, Wq, Wk, Wv, Wpk);

    hipLaunchKernelGGL(conv_mfma, dim3(8, 7, 16), dim3(256), 0, stream,
                       x, Wpk, qg, qb, qm, qv, vg, vb, vm, vva,
                       qbuf, kbuf, vbuf);

    hipLaunchKernelGGL(softmax_kernel, dim3(BB * 16), dim3(256), 0, stream, kbuf);

    hipLaunchKernelGGL(lambdac_kernel, dim3(1024), dim3(256), 0, stream,
                       kbuf, vbuf, lcb);

    hipLaunchKernelGGL(final_kernel, dim3(LL / FT_N, HEADS, BB), dim3(256), 0, stream,
                       qbuf, vbuf, lcb, emb, out);
}